// Round 1
// baseline (7967.442 us; speedup 1.0000x reference)
//
#include <hip/hip_runtime.h>
#include <stdint.h>

typedef __attribute__((ext_vector_type(8))) short short8;
typedef __attribute__((ext_vector_type(4))) float f32x4;
typedef unsigned int uint32;
typedef unsigned short ushort16;

#define SEQ 512
#define BATCH 128
#define DIN 512
#define DH 1024
#define DOUT 256

// ---- workspace layout (bytes) ----
#define XW_OFF   0u
#define XW_BYTES 134217728u            // 65536*1024*2 (bf16 xW)
#define WH_OFF   (XW_OFF + XW_BYTES)
#define WH_BYTES 2097152u              // 1024*1024 bf16 (N x K row-major)
#define WX_OFF   (WH_OFF + WH_BYTES)
#define WX_BYTES 1048576u              // 1024*512 bf16
#define HB_OFF   (WX_OFF + WX_BYTES)
#define HB_BYTES 524288u               // 2 x 128 x 512 dwords (bf16x2 h buffers)
#define DN_OFF   (HB_OFF + HB_BYTES)
#define DN_BYTES 262144u               // 8 groups x 512 steps x 16-dword stride counters

__device__ __forceinline__ ushort16 f2bf(float f) {
  uint32 u = __float_as_uint(f);
  u = u + 0x7fffu + ((u >> 16) & 1u);
  return (ushort16)(u >> 16);
}
__device__ __forceinline__ float bf2f(ushort16 h) {
  return __uint_as_float(((uint32)h) << 16);
}
__device__ __forceinline__ uint32 packbf(float lo, float hi) {
  return (uint32)f2bf(lo) | ((uint32)f2bf(hi) << 16);
}
__device__ __forceinline__ float tanh_fast(float x) {
  // tanh(x) = 1 - 2/(exp(2x)+1); exact at +/-inf, ~1e-6 rel err
  float e = __expf(2.0f * x);
  return 1.0f - 2.0f / (e + 1.0f);
}

// ---------------------------------------------------------------------------
// K0: convert weights to bf16, pack h0, zero arrive counters
// ---------------------------------------------------------------------------
__global__ __launch_bounds__(256) void prep_kernel(
    const float* __restrict__ W_i2h, const float* __restrict__ hidden,
    ushort16* __restrict__ Wx, ushort16* __restrict__ Wh,
    uint32* __restrict__ hbuf, uint32* __restrict__ done) {
  int idx = blockIdx.x * 256 + threadIdx.x;
  // W_i2h: [1024][1536]; cols 0..511 -> Wx[n][k], cols 512..1535 -> Wh[n][k]
  if (idx < DH * (DIN + DH)) {
    int row = idx / (DIN + DH);
    int col = idx - row * (DIN + DH);
    float v = W_i2h[idx];
    if (col < DIN) Wx[row * DIN + col] = f2bf(v);
    else           Wh[row * DH + (col - DIN)] = f2bf(v);
  }
  if (idx < BATCH * (DH / 2)) {        // 65536: pack h0 into buffer 0
    int b = idx >> 9, dk = idx & 511;
    hbuf[idx] = packbf(hidden[b * DH + dk * 2], hidden[b * DH + dk * 2 + 1]);
  }
  if (idx < 65536) done[idx] = 0u;     // zero full counter region
}

// ---------------------------------------------------------------------------
// K1: xW = x @ Wx^T  (M=65536, N=1024, K=512), bf16 in/out, fp32 accum
// 128x128 tile, 4 waves x (64x64), BK=64, single-buffered LDS
// ---------------------------------------------------------------------------
__global__ __launch_bounds__(256) void xw_gemm_kernel(
    const float* __restrict__ x, const ushort16* __restrict__ Wx,
    ushort16* __restrict__ xw) {
  __shared__ __attribute__((aligned(16))) ushort16 Al[128 * 72]; // pad 64->72
  __shared__ __attribute__((aligned(16))) ushort16 Bl[128 * 72];
  const int tid = threadIdx.x;
  const int lane = tid & 63;
  const int wv = tid >> 6;
  const int mh = wv & 1, nh = wv >> 1;
  const int bm = blockIdx.x >> 3;      // 512 M-tiles
  const int bn = blockIdx.x & 7;       // 8 N-tiles

  f32x4 acc[4][4];
#pragma unroll
  for (int i = 0; i < 4; ++i)
#pragma unroll
    for (int j = 0; j < 4; ++j) acc[i][j] = (f32x4){0.f, 0.f, 0.f, 0.f};

  uint32* Al32 = (uint32*)Al;

  for (int ko = 0; ko < DIN; ko += 64) {
    // stage A: 128 rows x 64 fp32 -> bf16 LDS
#pragma unroll
    for (int i = 0; i < 8; ++i) {
      int linear = i * 256 + tid;                 // 0..2047 float4s
      int row = linear >> 4, c4 = linear & 15;
      const float4 v = *(const float4*)(x + (size_t)(bm * 128 + row) * DIN + ko + c4 * 4);
      uint2 p;
      p.x = packbf(v.x, v.y);
      p.y = packbf(v.z, v.w);
      *(uint2*)(Al32 + row * 36 + c4 * 2) = p;
    }
    // stage B: 128 rows x 64 bf16
#pragma unroll
    for (int i = 0; i < 4; ++i) {
      int linear = i * 256 + tid;                 // 0..1023 short8s
      int row = linear >> 3, c8 = linear & 7;
      short8 v = *(const short8*)(Wx + (size_t)(bn * 128 + row) * DIN + ko + c8 * 8);
      *(short8*)(Bl + row * 72 + c8 * 8) = v;
    }
    __syncthreads();
#pragma unroll
    for (int kk = 0; kk < 64; kk += 32) {
      short8 af[4], bfv[4];
      const int kb = kk + ((lane >> 4) * 8);
#pragma unroll
      for (int mt = 0; mt < 4; ++mt)
        af[mt] = *(const short8*)(Al + (mh * 64 + mt * 16 + (lane & 15)) * 72 + kb);
#pragma unroll
      for (int nt = 0; nt < 4; ++nt)
        bfv[nt] = *(const short8*)(Bl + (nh * 64 + nt * 16 + (lane & 15)) * 72 + kb);
#pragma unroll
      for (int mt = 0; mt < 4; ++mt)
#pragma unroll
        for (int nt = 0; nt < 4; ++nt)
          acc[mt][nt] = __builtin_amdgcn_mfma_f32_16x16x32_bf16(af[mt], bfv[nt], acc[mt][nt], 0, 0, 0);
    }
    __syncthreads();
  }
  // epilogue: pair cols via shfl_xor(1), even lanes store packed dwords
#pragma unroll
  for (int mt = 0; mt < 4; ++mt)
#pragma unroll
    for (int nt = 0; nt < 4; ++nt)
#pragma unroll
      for (int r = 0; r < 4; ++r) {
        float v = acc[mt][nt][r];
        float o = __shfl_xor(v, 1);
        if (!(lane & 1)) {
          int m = bm * 128 + mh * 64 + mt * 16 + ((lane >> 4) * 4) + r;
          int c = bn * 128 + nh * 64 + nt * 16 + (lane & 15);
          ((uint32*)xw)[(size_t)m * 512 + (c >> 1)] = packbf(v, o);
        }
      }
}

// ---------------------------------------------------------------------------
// K2: recurrence. 256 blocks = 8 groups (blockIdx%8, XCD-local) x 32 blocks.
// Block: rows g*16..+16, cols w*32..+32. 4 waves: (col-tile ct) x (K-half kh).
// Wh fragments live in registers; h exchanged via agent-scope atomics.
// ---------------------------------------------------------------------------
__global__ __launch_bounds__(256) void rnn_kernel(
    const ushort16* __restrict__ xw, const ushort16* __restrict__ Wh,
    const float* __restrict__ b_i2h,
    uint32* hbuf, uint32* done, float* __restrict__ h_out) {
  const int g = blockIdx.x & 7;
  const int w = blockIdx.x >> 3;
  const int lane = threadIdx.x & 63;
  const int q = threadIdx.x >> 6;
  const int ct = q & 1, kh = q >> 1;
  const int colbase = w * 32 + ct * 16;
  const int bcol = colbase + (lane & 15);
  const int rowloc = (lane >> 4) * 4;

  __shared__ __attribute__((aligned(16))) ushort16 h_lds[16 * 1032]; // stride 1032 bf16 (pad 16B)
  __shared__ __attribute__((aligned(16))) float red[640];            // [ct][col*20+row]

  // preload Wh fragments: wave (ct,kh) needs cols [colbase,+16), k in [kh*512,+512)
  short8 bfrag[16];
#pragma unroll
  for (int ks = 0; ks < 16; ++ks) {
    int k = kh * 512 + ks * 32 + ((lane >> 4) * 8);
    bfrag[ks] = *(const short8*)(Wh + (size_t)bcol * DH + k);
  }
  const float biasv = b_i2h[bcol];
  uint32* hl32 = (uint32*)h_lds;

  for (int t = 1; t <= SEQ; ++t) {
    const int s = t - 1;
    // issue xW loads early (independent of h) — HBM latency hides under spin
    float xwv[4];
    if (kh == 0) {
#pragma unroll
      for (int r = 0; r < 4; ++r) {
        int b = g * 16 + rowloc + r;
        xwv[r] = bf2f(xw[(size_t)(s * BATCH + b) * DH + bcol]);
      }
    }
    // wait for h_{t-1} (64 arrivals: 2 publishing waves x 32 blocks)
    if (t > 1) {
      uint32* cp = done + (size_t)(g * SEQ + (t - 2)) * 16;
      uint32 v;
      do {
        v = 0;
        if (lane == 0)
          v = __hip_atomic_load(cp, __ATOMIC_RELAXED, __HIP_MEMORY_SCOPE_AGENT);
        v = __shfl(v, 0);
      } while (v < 64u);
    }
    // stage h -> LDS: wave q loads dword-quarter [q*128,+128) of each of 16 rows
    {
      uint32* hsrc = hbuf + ((s & 1) ? 65536 : 0);
      const int base = q * 128;
#pragma unroll
      for (int i = 0; i < 32; ++i) {
        int linear = i * 64 + lane;
        int row = linear >> 7, dk = linear & 127;
        uint32 vv = __hip_atomic_load(hsrc + (size_t)(g * 16 + row) * 512 + base + dk,
                                      __ATOMIC_RELAXED, __HIP_MEMORY_SCOPE_AGENT);
        hl32[row * 516 + base + dk] = vv;
      }
    }
    __syncthreads();
    // MFMA: 16 K-steps over this wave's K-half
    f32x4 acc = (f32x4){0.f, 0.f, 0.f, 0.f};
#pragma unroll
    for (int ks = 0; ks < 16; ++ks) {
      int kbyte = (kh * 512 + ks * 32 + ((lane >> 4) * 8)) * 2;
      short8 af = *(const short8*)((const char*)h_lds + (lane & 15) * 2064 + kbyte);
      acc = __builtin_amdgcn_mfma_f32_16x16x32_bf16(af, bfrag[ks], acc, 0, 0, 0);
    }
    if (kh == 1)
      *(f32x4*)(red + ct * 320 + (lane & 15) * 20 + rowloc) = acc;
    __syncthreads();
    if (kh == 0) {
      f32x4 p = *(const f32x4*)(red + ct * 320 + (lane & 15) * 20 + rowloc);
      float hv[4];
#pragma unroll
      for (int r = 0; r < 4; ++r)
        hv[r] = tanh_fast(acc[r] + p[r] + biasv + xwv[r]);
      // publish h_t (packed bf16x2, agent-scope)
      uint32* hdst = hbuf + ((t & 1) ? 65536 : 0);
#pragma unroll
      for (int r = 0; r < 4; ++r) {
        float o = __shfl_xor(hv[r], 1);
        if (!(lane & 1)) {
          int b = g * 16 + rowloc + r;
          __hip_atomic_store(hdst + (size_t)b * 512 + ((colbase + (lane & 15)) >> 1),
                             packbf(hv[r], o), __ATOMIC_RELAXED, __HIP_MEMORY_SCOPE_AGENT);
        }
      }
      if (t == SEQ) {
#pragma unroll
        for (int r = 0; r < 4; ++r) {
          int b = g * 16 + rowloc + r;
          h_out[(size_t)b * DH + bcol] = hv[r];
        }
      }
      if (lane == 0)
        __hip_atomic_fetch_add(done + (size_t)(g * SEQ + (t - 1)) * 16, 1u,
                               __ATOMIC_RELEASE, __HIP_MEMORY_SCOPE_AGENT);
    }
  }
}

// ---------------------------------------------------------------------------
// K3: logits = h_final @ W_h2o^T + b; row softmax. 1 block per batch row.
// ---------------------------------------------------------------------------
__global__ __launch_bounds__(256) void head_kernel(
    const float* __restrict__ hfin, const float* __restrict__ W,
    const float* __restrict__ bias, float* __restrict__ out) {
  __shared__ __attribute__((aligned(16))) float hrow[DH];
  __shared__ float rbuf[256];
  const int b = blockIdx.x;
  const int tid = threadIdx.x;
  for (int i = tid; i < DH; i += 256) hrow[i] = hfin[(size_t)b * DH + i];
  __syncthreads();
  float s = bias[tid];
  const float4* wr = (const float4*)(W + (size_t)tid * DH);
#pragma unroll 4
  for (int k = 0; k < DH / 4; ++k) {
    float4 wv = wr[k];
    float4 hv = *(const float4*)(hrow + k * 4);
    s += wv.x * hv.x + wv.y * hv.y + wv.z * hv.z + wv.w * hv.w;
  }
  rbuf[tid] = s;
  __syncthreads();
  for (int off = 128; off > 0; off >>= 1) {
    if (tid < off) rbuf[tid] = fmaxf(rbuf[tid], rbuf[tid + off]);
    __syncthreads();
  }
  float mx = rbuf[0];
  __syncthreads();
  float e = __expf(s - mx);
  rbuf[tid] = e;
  __syncthreads();
  for (int off = 128; off > 0; off >>= 1) {
    if (tid < off) rbuf[tid] += rbuf[tid + off];
    __syncthreads();
  }
  out[(size_t)b * DOUT + tid] = e / rbuf[0];
}

// ---------------------------------------------------------------------------
extern "C" void kernel_launch(void* const* d_in, const int* in_sizes, int n_in,
                              void* d_out, int out_size, void* d_ws, size_t ws_size,
                              hipStream_t stream) {
  const float* x      = (const float*)d_in[0];
  const float* hidden = (const float*)d_in[1];
  const float* W_i2h  = (const float*)d_in[2];
  const float* b_i2h  = (const float*)d_in[3];
  const float* W_h2o  = (const float*)d_in[4];
  const float* b_h2o  = (const float*)d_in[5];
  float* out = (float*)d_out;

  char* ws = (char*)d_ws;
  ushort16* xw   = (ushort16*)(ws + XW_OFF);
  ushort16* Wh   = (ushort16*)(ws + WH_OFF);
  ushort16* Wx   = (ushort16*)(ws + WX_OFF);
  uint32*   hbuf = (uint32*)(ws + HB_OFF);
  uint32*   done = (uint32*)(ws + DN_OFF);

  prep_kernel<<<6144, 256, 0, stream>>>(W_i2h, hidden, Wx, Wh, hbuf, done);
  xw_gemm_kernel<<<4096, 256, 0, stream>>>(x, Wx, xw);
  rnn_kernel<<<256, 256, 0, stream>>>(xw, Wh, b_i2h, hbuf, done, out + BATCH * DOUT);
  head_kernel<<<128, 256, 0, stream>>>(out + BATCH * DOUT, W_h2o, b_h2o, out);
}